// Round 7
// baseline (345.351 us; speedup 1.0000x reference)
//
#include <hip/hip_runtime.h>

// CrossAttention: B=4, C=256, H=W=64, N=4096, fp32 in/out.
// ws: Qf16 [B,N,C] @0MB, Kf16 [B,N,C] @8MB, Vt f16 [B,C,N] @16MB, Wf16 [3][O][C] @24MB

typedef __attribute__((ext_vector_type(8))) short short8;
typedef __attribute__((ext_vector_type(4))) float f32x4;
typedef __attribute__((ext_vector_type(16))) float f32x16;
typedef __attribute__((ext_vector_type(4))) int int4v;
typedef __attribute__((ext_vector_type(8))) _Float16 half8;

#define LOG2E 1.44269504089f

static __device__ __forceinline__ float exp2_fast(float x){ return __builtin_amdgcn_exp2f(x); }

static __device__ __forceinline__ int pk_f16(float a, float b){
  auto h = __builtin_amdgcn_cvt_pkrtz(a, b);   // low=a, high=b
  return __builtin_bit_cast(int, h);
}
static __device__ __forceinline__ unsigned short f2h(float v){
  return __builtin_bit_cast(unsigned short, (_Float16)v);
}

#define GLOAD16(gp, lp) __builtin_amdgcn_global_load_lds( \
  (const __attribute__((address_space(1))) void*)(gp),    \
  (__attribute__((address_space(3))) void*)(lp), 16, 0, 0)

#define MFMA32(a,b,c) __builtin_amdgcn_mfma_f32_16x16x32_f16( \
  __builtin_bit_cast(half8, a), __builtin_bit_cast(half8, b), c, 0, 0, 0)
#define MFMA3216(a,b,c) __builtin_amdgcn_mfma_f32_32x32x16_f16( \
  __builtin_bit_cast(half8, (a)), __builtin_bit_cast(half8, (b)), (c), 0, 0, 0)

// ---------------------------------------------------------------- W -> f16
__global__ __launch_bounds__(256) void cvt_w(
    const float* __restrict__ wq, const float* __restrict__ wk,
    const float* __restrict__ wv, unsigned short* __restrict__ wf)
{
  const int o = blockIdx.x, t = blockIdx.y, c = threadIdx.x;
  const float* w = (t == 0) ? wq : ((t == 1) ? wk : wv);
  wf[t*65536 + o*256 + c] = f2h(w[o*256 + c]);
}

// ---------------------------------------------------------------- projections (f16 MFMA)
// t=0: Q=Wq*x -> qf [B,N,C]; t=1: K=Wk*y -> kf [B,N,C]; t=2: V=Wv*y -> vtf [B,C,N]
__global__ __launch_bounds__(256, 2) void proj_kernel(
    const float* __restrict__ x, const float* __restrict__ y,
    const unsigned short* __restrict__ wf,
    const float* __restrict__ bq, const float* __restrict__ bk, const float* __restrict__ bv,
    unsigned short* __restrict__ qf, unsigned short* __restrict__ kf,
    unsigned short* __restrict__ vtf)
{
  __shared__ float xs[256*64];   // 64KB

  const int t   = blockIdx.z;
  const int b   = blockIdx.y;
  const int n0  = blockIdx.x * 64;
  const int tid = threadIdx.x;
  const int w   = tid >> 6, lane = tid & 63, g = lane >> 4, l15 = lane & 15;

  const float* src = ((t == 0) ? x : y) + (size_t)b*1048576 + n0;

  // stage 64KB with rotated rows: LDS[c][nn] = x[c][(nn - 16*((c>>3)&3)) & 63]
  #pragma unroll
  for (int i = 0; i < 16; i++){
    int c  = i*16 + (tid >> 4);
    int gg = (c >> 3) & 3;
    int sg = ((tid & 15) - 4*gg) & 15;
    GLOAD16((const char*)src + (size_t)c*16384 + sg*16,
            (char*)xs + (i*256 + tid)*16);
  }
  __syncthreads();

  // x^T fragments: row n_l=l15 (n = n0+w*16+l15), k = cs*32 + g*8 + j
  int4v xf[8];
  {
    const int nn = (w*16 + l15 + 16*g) & 63;
    #pragma unroll
    for (int cs = 0; cs < 8; cs++){
      float v[8];
      #pragma unroll
      for (int j = 0; j < 8; j++) v[j] = xs[(cs*32 + g*8 + j)*64 + nn];
      int4v f;
      f[0] = pk_f16(v[0], v[1]); f[1] = pk_f16(v[2], v[3]);
      f[2] = pk_f16(v[4], v[5]); f[3] = pk_f16(v[6], v[7]);
      xf[cs] = f;
    }
  }

  const unsigned short* wt = wf + t*65536;
  const float* bias = (t == 0) ? bq : ((t == 1) ? bk : bv);

  #pragma unroll 4
  for (int ot = 0; ot < 16; ot++){
    f32x4 acc;
    if (t < 2){
      float bo = bias[ot*16 + l15];
      acc = (f32x4){bo, bo, bo, bo};
    } else {
      acc = *(const f32x4*)&bias[ot*16 + g*4];
    }
    #pragma unroll
    for (int cs = 0; cs < 8; cs++){
      short8 wfr = *(const short8*)&wt[(ot*16 + l15)*256 + cs*32 + g*8];
      if (t < 2) acc = MFMA32(__builtin_bit_cast(short8, xf[cs]), wfr, acc);  // D[n][o]
      else       acc = MFMA32(wfr, __builtin_bit_cast(short8, xf[cs]), acc);  // D[o][n]
    }
    if (t < 2){
      unsigned short* outp = (t == 0) ? qf : kf;
      #pragma unroll
      for (int r = 0; r < 4; r++){
        int n = n0 + w*16 + g*4 + r;
        outp[((size_t)(b*4096 + n))*256 + ot*16 + l15] = f2h(acc[r]);
      }
    } else {
      #pragma unroll
      for (int r = 0; r < 4; r++){
        int o = ot*16 + g*4 + r;
        vtf[((size_t)(b*256 + o))*4096 + n0 + w*16 + l15] = f2h(acc[r]);
      }
    }
  }
}

// ---------------------------------------------------------------- attention
// grid 256 (XCD-swizzled -> (b, ntile)), 512 thr = 4 KV-quarters x 2 q-waves.
// 32x32x16 MFMA; K,V read DIRECT from L2 (no in-loop LDS, no vmcnt-drain
// barriers). Wave: 32 q-rows x 1024 KV rows, KVBLK=32 (32 iters).
// Softmax in-register (16 scores/lane + 1 shfl_xor); P->B-frag via
// cvt_pk + shfl_xor(32) half-exchange. LDS only for 4-quarter merge epilogue.
__global__ __launch_bounds__(512, 2) void attn_kernel(
    const unsigned short* __restrict__ qf, const unsigned short* __restrict__ kf,
    const unsigned short* __restrict__ vtf,
    float* __restrict__ out)
{
  __shared__ float lds_o[2][2][8][64][16];   // 128KB (epilogue only)
  __shared__ float lds_ml[2][2][64][2];      // 2KB

  const int tid  = threadIdx.x;
  const int w    = tid >> 6, lane = tid & 63, l31 = lane & 31, h = lane >> 5;
  const int kg   = w >> 1, wq = w & 1;

  // XCD-bijective swizzle: XCD x serves batch x>>1 -> K+V (4MB) pinned in 2 XCDs' L2
  const int bid = blockIdx.x;
  const int xcd = bid & 7, slot = bid >> 3;
  const int b   = xcd >> 1;
  const int n0  = ((xcd & 1) * 32 + slot) * 64;

  // Q fragments (B-operand): n = qrow, k = c = kc*16 + h*8 + j
  const int qrow = n0 + wq*32 + l31;
  const unsigned short* qp = qf + ((size_t)(b*4096 + qrow))*256 + h*8;
  short8 qr[16];
  #pragma unroll
  for (int kc = 0; kc < 16; kc++) qr[kc] = *(const short8*)(qp + kc*16);

  f32x16 o[8];
  #pragma unroll
  for (int i = 0; i < 8; i++)
    #pragma unroll
    for (int r = 0; r < 16; r++) o[i][r] = 0.f;
  float mrun = -1e30f, lrun = 0.f;

  const int kv0 = kg * 1024;
  const unsigned short* kp = kf  + ((size_t)(b*4096 + kv0 + l31))*256 + h*8;
  const unsigned short* vp = vtf + ((size_t)(b*256 + l31))*4096 + kv0 + h*8;

  for (int it = 0; it < 32; ++it){
    const unsigned short* kpi = kp + it*8192;

    // ---- QK^T (swapped): S^T[m][n] = sum_c K[m,c] Q[n,c]; two acc chains
    f32x16 sa, sb;
    #pragma unroll
    for (int r = 0; r < 16; r++){ sa[r] = 0.f; sb[r] = 0.f; }
    __builtin_amdgcn_s_setprio(1);
    #pragma unroll
    for (int kc = 0; kc < 16; kc += 2){
      short8 k0 = *(const short8*)(kpi + kc*16);
      short8 k1 = *(const short8*)(kpi + kc*16 + 16);
      sa = MFMA3216(k0, qr[kc],     sa);
      sb = MFMA3216(k1, qr[kc + 1], sb);
    }
    __builtin_amdgcn_s_setprio(0);
    f32x16 s = sa + sb;

    // ---- online softmax: lane holds 16 of 32 m-scores for q-col n=l31
    float tm = fmaxf(fmaxf(fmaxf(s[0],s[1]), fmaxf(s[2],s[3])),
                     fmaxf(fmaxf(s[4],s[5]), fmaxf(s[6],s[7])));
    tm = fmaxf(tm, fmaxf(fmaxf(fmaxf(s[8],s[9]),   fmaxf(s[10],s[11])),
                         fmaxf(fmaxf(s[12],s[13]), fmaxf(s[14],s[15]))));
    tm = fmaxf(tm, __shfl_xor(tm, 32));

    if (__any(tm > mrun)){
      float mn = fmaxf(mrun, tm);
      float sc = exp2_fast((mrun - mn) * LOG2E);
      lrun *= sc;
      #pragma unroll
      for (int i = 0; i < 8; i++) o[i] *= sc;
      mrun = mn;
    }
    const float mb = mrun * LOG2E;
    #pragma unroll
    for (int r = 0; r < 16; r++) s[r] = exp2_fast(s[r]*LOG2E - mb);

    float ps = (((s[0]+s[1])+(s[2]+s[3])) + ((s[4]+s[5])+(s[6]+s[7])))
             + (((s[8]+s[9])+(s[10]+s[11])) + ((s[12]+s[13])+(s[14]+s[15])));
    ps += __shfl_xor(ps, 32);
    lrun += ps;

    // ---- P -> PV B-fragments: pack pairs (m-adjacent), exchange halves
    // reg r holds m = (r&3) + 8*(r>>2) + 4h  =>  A_i pairs: {0,1},{2,3},{8,9},...(+4h)
    int A0 = pk_f16(s[0], s[1]),   A1 = pk_f16(s[2], s[3]);
    int A2 = pk_f16(s[4], s[5]),   A3 = pk_f16(s[6], s[7]);
    int A4 = pk_f16(s[8], s[9]),   A5 = pk_f16(s[10], s[11]);
    int A6 = pk_f16(s[12], s[13]), A7 = pk_f16(s[14], s[15]);
    int S0 = __shfl_xor(A0, 32), S1 = __shfl_xor(A1, 32);
    int S2 = __shfl_xor(A2, 32), S3 = __shfl_xor(A3, 32);
    int S4 = __shfl_xor(A4, 32), S5 = __shfl_xor(A5, 32);
    int S6 = __shfl_xor(A6, 32), S7 = __shfl_xor(A7, 32);
    // B-frag k = h*8+j: kchunk0 -> m 0..15, kchunk1 -> m 16..31
    int4v pb0 = { h ? S2 : A0, h ? S3 : A1, h ? A2 : S0, h ? A3 : S1 };
    int4v pb1 = { h ? S6 : A4, h ? S7 : A5, h ? A6 : S4, h ? A7 : S5 };

    // ---- PV: O^T[c][n] += sum_m V^T[c,m] P[n,m]  (V^T rows direct from L2)
    const unsigned short* vpi = vp + it*32;
    __builtin_amdgcn_s_setprio(1);
    #pragma unroll
    for (int ct = 0; ct < 8; ct++){
      short8 v0 = *(const short8*)(vpi + ct*131072);
      short8 v1 = *(const short8*)(vpi + ct*131072 + 16);
      o[ct] = MFMA3216(v0, pb0, o[ct]);
      o[ct] = MFMA3216(v1, pb1, o[ct]);
    }
    __builtin_amdgcn_s_setprio(0);

    __builtin_amdgcn_s_barrier();   // loose sync: sibling waves share L1 tiles
  }

  // ---- 4-quarter tree merge via LDS (f32 partials, swizzled chunks)
  const int swz = (lane >> 1) & 3;

  __syncthreads();
  if (kg & 1){                       // kg 1 -> slot 0, kg 3 -> slot 1
    const int sl = kg >> 1;
    #pragma unroll
    for (int ct = 0; ct < 8; ct++)
      #pragma unroll
      for (int c4 = 0; c4 < 4; c4++){
        f32x4 v = { o[ct][c4*4], o[ct][c4*4+1], o[ct][c4*4+2], o[ct][c4*4+3] };
        *(f32x4*)&lds_o[sl][wq][ct][lane][(c4 ^ swz)*4] = v;
      }
    lds_ml[sl][wq][lane][0] = mrun;
    lds_ml[sl][wq][lane][1] = lrun;
  }
  __syncthreads();
  if (!(kg & 1)){                    // kg 0 merges slot 0, kg 2 merges slot 1
    const int sl = kg >> 1;
    float m1 = lds_ml[sl][wq][lane][0];
    float l1 = lds_ml[sl][wq][lane][1];
    float m  = fmaxf(mrun, m1);
    float sca = exp2_fast((mrun - m) * LOG2E);
    float scb = exp2_fast((m1   - m) * LOG2E);
    #pragma unroll
    for (int ct = 0; ct < 8; ct++)
      #pragma unroll
      for (int c4 = 0; c4 < 4; c4++){
        f32x4 v = *(const f32x4*)&lds_o[sl][wq][ct][lane][(c4 ^ swz)*4];
        #pragma unroll
        for (int j = 0; j < 4; j++) o[ct][c4*4+j] = o[ct][c4*4+j]*sca + v[j]*scb;
      }
    mrun = m;
    lrun = lrun*sca + l1*scb;
  }
  __syncthreads();
  if (kg == 2){                      // republish merged (2,3) to slot 1
    #pragma unroll
    for (int ct = 0; ct < 8; ct++)
      #pragma unroll
      for (int c4 = 0; c4 < 4; c4++){
        f32x4 v = { o[ct][c4*4], o[ct][c4*4+1], o[ct][c4*4+2], o[ct][c4*4+3] };
        *(f32x4*)&lds_o[1][wq][ct][lane][(c4 ^ swz)*4] = v;
      }
    lds_ml[1][wq][lane][0] = mrun;
    lds_ml[1][wq][lane][1] = lrun;
  }
  __syncthreads();
  if (kg == 0){                      // final merge + write out[b, c, n]
    float m1 = lds_ml[1][wq][lane][0];
    float l1 = lds_ml[1][wq][lane][1];
    float m  = fmaxf(mrun, m1);
    float sca = exp2_fast((mrun - m) * LOG2E);
    float scb = exp2_fast((m1   - m) * LOG2E);
    float rl  = 1.0f / (lrun*sca + l1*scb);
    sca *= rl; scb *= rl;
    #pragma unroll
    for (int ct = 0; ct < 8; ct++){
      #pragma unroll
      for (int c4 = 0; c4 < 4; c4++){
        f32x4 v = *(const f32x4*)&lds_o[1][wq][ct][lane][(c4 ^ swz)*4];
        #pragma unroll
        for (int j = 0; j < 4; j++){
          int r = c4*4 + j;
          int c = ct*32 + (r & 3) + 8*(r >> 2) + 4*h;
          out[((size_t)(b*256 + c))*4096 + n0 + wq*32 + l31] = o[ct][r]*sca + v[j]*scb;
        }
      }
    }
  }
}

// ---------------------------------------------------------------- launch
extern "C" void kernel_launch(void* const* d_in, const int* in_sizes, int n_in,
                              void* d_out, int out_size, void* d_ws, size_t ws_size,
                              hipStream_t stream)
{
  const float* x  = (const float*)d_in[0];
  const float* y  = (const float*)d_in[1];
  const float* Wq = (const float*)d_in[2];
  const float* bq = (const float*)d_in[3];
  const float* Wk = (const float*)d_in[4];
  const float* bk = (const float*)d_in[5];
  const float* Wv = (const float*)d_in[6];
  const float* bv = (const float*)d_in[7];
  float* out = (float*)d_out;

  char* ws = (char*)d_ws;
  const size_t MB = 1048576;
  unsigned short* qf  = (unsigned short*)(ws + 0*MB);
  unsigned short* kfp = (unsigned short*)(ws + 8*MB);
  unsigned short* vtf = (unsigned short*)(ws + 16*MB);
  unsigned short* wf  = (unsigned short*)(ws + 24*MB);

  cvt_w<<<dim3(256,3), dim3(256), 0, stream>>>(Wq, Wk, Wv, wf);
  proj_kernel<<<dim3(64,4,3), dim3(256), 0, stream>>>(x, y, wf, bq, bk, bv,
                                                      qf, kfp, vtf);
  attn_kernel<<<dim3(256), dim3(512), 0, stream>>>(qf, kfp, vtf, out);
}

// Round 8
// 256.681 us; speedup vs baseline: 1.3454x; 1.3454x over previous
//
#include <hip/hip_runtime.h>

// CrossAttention: B=4, C=256, H=W=64, N=4096, fp32 in/out.
// ws (byte offsets): qf 0, kf 8MiB, vtf 16MiB, wf 24MiB (384KiB),
//                    partials f16 @25559040 (16MiB), ml f32 @42336256 (256KiB)

typedef __attribute__((ext_vector_type(8))) short short8;
typedef __attribute__((ext_vector_type(4))) float f32x4;
typedef __attribute__((ext_vector_type(4))) int int4v;
typedef __attribute__((ext_vector_type(2))) int int2v;
typedef __attribute__((ext_vector_type(8))) _Float16 half8;

#define LOG2E 1.44269504089f

static __device__ __forceinline__ float exp2_fast(float x){ return __builtin_amdgcn_exp2f(x); }

static __device__ __forceinline__ int pk_f16(float a, float b){
  auto h = __builtin_amdgcn_cvt_pkrtz(a, b);   // low=a, high=b
  return __builtin_bit_cast(int, h);
}
static __device__ __forceinline__ unsigned short f2h(float v){
  return __builtin_bit_cast(unsigned short, (_Float16)v);
}

#define GLOAD16(gp, lp) __builtin_amdgcn_global_load_lds( \
  (const __attribute__((address_space(1))) void*)(gp),    \
  (__attribute__((address_space(3))) void*)(lp), 16, 0, 0)

#define MFMAF16(a,b,c) __builtin_amdgcn_mfma_f32_16x16x32_f16( \
  __builtin_bit_cast(half8, a), __builtin_bit_cast(half8, b), c, 0, 0, 0)

// ---------------------------------------------------------------- W -> f16
__global__ __launch_bounds__(256) void cvt_w(
    const float* __restrict__ wq, const float* __restrict__ wk,
    const float* __restrict__ wv, unsigned short* __restrict__ wf)
{
  const int o = blockIdx.x, t = blockIdx.y, c = threadIdx.x;
  const float* w = (t == 0) ? wq : ((t == 1) ? wk : wv);
  wf[t*65536 + o*256 + c] = f2h(w[o*256 + c]);
}

// ---------------------------------------------------------------- projections (f16 MFMA)
// t=0: Q=Wq*x -> qf [B,N,C]; t=1: K=Wk*y -> kf [B,N,C]; t=2: V=Wv*y -> vtf [B,C,N]
// x-tile rotated in LDS (as r6); W streamed through LDS dbuf (8KB/ot, swizzled).
__global__ __launch_bounds__(256, 2) void proj_kernel(
    const float* __restrict__ x, const float* __restrict__ y,
    const unsigned short* __restrict__ wf,
    const float* __restrict__ bq, const float* __restrict__ bk, const float* __restrict__ bv,
    unsigned short* __restrict__ qf, unsigned short* __restrict__ kf,
    unsigned short* __restrict__ vtf)
{
  __shared__ float xs[256*64];       // 64KB
  __shared__ short wlds[2][4096];    // 2 x 8KB W tiles

  const int t   = blockIdx.z;
  const int b   = blockIdx.y;
  const int n0  = blockIdx.x * 64;
  const int tid = threadIdx.x;
  const int w   = tid >> 6, lane = tid & 63, g = lane >> 4, l15 = lane & 15;

  const float* src = ((t == 0) ? x : y) + (size_t)b*1048576 + n0;
  const char*  wt_b = (const char*)(wf + t*65536);

  // W stage: seg s = w*2+i (1KB each); row = s*2 + (lane>>5); pre-swizzled src
  int wsrc[2];
  #pragma unroll
  for (int i = 0; i < 2; i++){
    int s = w*2 + i;
    int row = s*2 + (lane >> 5);
    wsrc[i] = row*512 + (((lane & 31)*16) ^ ((row & 7) << 4));
  }

  // stage x 64KB with rotated rows + W tile 0
  #pragma unroll
  for (int i = 0; i < 16; i++){
    int c  = i*16 + (tid >> 4);
    int gg = (c >> 3) & 3;
    int sg = ((tid & 15) - 4*gg) & 15;
    GLOAD16((const char*)src + (size_t)c*16384 + sg*16,
            (char*)xs + (i*256 + tid)*16);
  }
  #pragma unroll
  for (int i = 0; i < 2; i++){
    int s = w*2 + i;
    GLOAD16(wt_b + wsrc[i], (char*)&wlds[0][0] + s*1024);
  }
  __syncthreads();

  // x^T fragments
  int4v xf[8];
  {
    const int nn = (w*16 + l15 + 16*g) & 63;
    #pragma unroll
    for (int cs = 0; cs < 8; cs++){
      float v[8];
      #pragma unroll
      for (int j = 0; j < 8; j++) v[j] = xs[(cs*32 + g*8 + j)*64 + nn];
      int4v f;
      f[0] = pk_f16(v[0], v[1]); f[1] = pk_f16(v[2], v[3]);
      f[2] = pk_f16(v[4], v[5]); f[3] = pk_f16(v[6], v[7]);
      xf[cs] = f;
    }
  }

  const float* bias = (t == 0) ? bq : ((t == 1) ? bk : bv);

  int buf = 0;
  for (int ot = 0; ot < 16; ot++){
    if (ot < 15){
      #pragma unroll
      for (int i = 0; i < 2; i++){
        int s = w*2 + i;
        GLOAD16(wt_b + (ot+1)*8192 + wsrc[i], (char*)&wlds[buf^1][0] + s*1024);
      }
    }

    f32x4 acc;
    if (t < 2){
      float bo = bias[ot*16 + l15];
      acc = (f32x4){bo, bo, bo, bo};
    } else {
      acc = *(const f32x4*)&bias[ot*16 + g*4];
    }
    const char* wb = (const char*)&wlds[buf][0];
    #pragma unroll
    for (int cs = 0; cs < 8; cs++){
      short8 wfr = *(const short8*)(wb + (l15*512 + ((cs*64 + g*16) ^ ((l15 & 7) << 4))));
      if (t < 2) acc = MFMAF16(__builtin_bit_cast(short8, xf[cs]), wfr, acc);  // D[n][o]
      else       acc = MFMAF16(wfr, __builtin_bit_cast(short8, xf[cs]), acc);  // D[o][n]
    }
    if (t < 2){
      unsigned short* outp = (t == 0) ? qf : kf;
      #pragma unroll
      for (int r = 0; r < 4; r++){
        int n = n0 + w*16 + g*4 + r;
        outp[((size_t)(b*4096 + n))*256 + ot*16 + l15] = f2h(acc[r]);
      }
    } else {
      #pragma unroll
      for (int r = 0; r < 4; r++){
        int o = ot*16 + g*4 + r;
        vtf[((size_t)(b*256 + o))*4096 + n0 + w*16 + l15] = f2h(acc[r]);
      }
    }
    __syncthreads();   // all done reading wlds[buf]; next tile (issued above) drained
    buf ^= 1;
  }
}

// ---------------------------------------------------------------- attention (partials)
// grid 256: xcd = bid&7 -> b = xcd>>1, KV-half hf = xcd&1; qt = bid>>3 (0..31).
// Block: 128 q-rows (8 waves x 16), single KV stream of 2048 rows, KVBLK=32,
// K/V dbuf in LDS (64KB) -> 2 blocks/CU, 4 waves/SIMD. Writes unnormalized
// O partials (f16) + (m,l); merge_kernel combines the two halves.
__global__ __launch_bounds__(512, 4) void attn_kernel(
    const unsigned short* __restrict__ qf, const unsigned short* __restrict__ kf,
    const unsigned short* __restrict__ vtf,
    unsigned short* __restrict__ part, float* __restrict__ mlbuf)
{
  __shared__ short k_s[2][32*256];   // [buf][m][c], rows 512B, swz ^((m&7)<<4)
  __shared__ short v_s[2][256*32];   // [buf][c][m], rows 64B,  swz ^(((c>>1)&3)<<4)

  const int tid  = threadIdx.x;
  const int w    = tid >> 6, lane = tid & 63, g = lane >> 4, col = lane & 15;
  const int bid  = blockIdx.x;
  const int xcd  = bid & 7, qt = bid >> 3;
  const int b    = xcd >> 1, hf = xcd & 1;

  // Q fragments: n = qt*128 + w*16 + col, 8 contiguous c per chunk
  short8 qh[8];
  {
    const size_t qoff = ((size_t)(b*4096 + qt*128 + w*16 + col))*256 + g*8;
    #pragma unroll
    for (int ch = 0; ch < 8; ch++)
      qh[ch] = *(const short8*)(qf + qoff + ch*32);
  }

  f32x4 o_acc[16];
  #pragma unroll
  for (int i = 0; i < 16; i++){
    o_acc[i][0]=0.f; o_acc[i][1]=0.f; o_acc[i][2]=0.f; o_acc[i][3]=0.f;
  }
  float mst = -1e30f, lst = 0.f;

  const int swzK = (col & 7) << 4;
  const int g16  = g << 4;
  const int kb0  = col * 512;
  const int kb1  = kb0 + 8192;
  const int vb   = col*64 + (g16 ^ (((col>>1)&3)<<4));

  const int laneA  = col + ((g & 1) ? 32 : 0);
  const int laneB  = laneA + 16;
  const bool selLow = (g < 2);

  // staging source offsets (pre-swizzled; 2 segs of 1KB per wave per tensor)
  int ksrc[2], vsrc[2];
  #pragma unroll
  for (int i = 0; i < 2; i++){
    int s = w*2 + i;
    int m = s*2 + (lane >> 5);
    ksrc[i] = m*512 + (((lane & 31)*16) ^ ((m & 7) << 4));
    int c = s*16 + (lane >> 2);
    vsrc[i] = c*8192 + (((lane & 3)*16) ^ (((lane >> 3) & 3) << 4));
  }

  const char* khg = (const char*)(kf + ((size_t)b*4096 + hf*2048)*256);
  const char* vg  = (const char*)(vtf + ((size_t)b*256)*4096) + hf*4096;

  // prologue: stage tile 0 into buf 0
  #pragma unroll
  for (int i = 0; i < 2; i++){
    int s = w*2 + i;
    GLOAD16(khg + ksrc[i], (char*)&k_s[0][0] + s*1024);
    GLOAD16(vg  + vsrc[i], (char*)&v_s[0][0] + s*1024);
  }

  int buf = 0;
  for (int it = 0; it < 64; ++it){
    __syncthreads();   // tile `it` staged (vmcnt drained before s_barrier)

    if (it < 63){      // prefetch next tile AFTER barrier -> overlaps compute
      const char* kht = khg + (size_t)(it+1)*16384;
      const char* vtt = vg  + (size_t)(it+1)*64;
      #pragma unroll
      for (int i = 0; i < 2; i++){
        int s = w*2 + i;
        GLOAD16(kht + ksrc[i], (char*)&k_s[buf^1][0] + s*1024);
        GLOAD16(vtt + vsrc[i], (char*)&v_s[buf^1][0] + s*1024);
      }
    }

    const char* kb   = (const char*)&k_s[buf][0];
    const char* vbuf = (const char*)&v_s[buf][0];

    // ---- QK^T (swapped): S^T[m][n] = sum_c K[m,c] Q[n,c]
    f32x4 s0 = {0.f,0.f,0.f,0.f};
    f32x4 s1 = {0.f,0.f,0.f,0.f};
    __builtin_amdgcn_s_setprio(1);
    #pragma unroll
    for (int ch = 0; ch < 8; ch++){
      int inr = ((ch << 6) | g16) ^ swzK;
      short8 kh0 = *(const short8*)(kb + kb0 + inr);
      short8 kh1 = *(const short8*)(kb + kb1 + inr);
      s0 = MFMAF16(kh0, qh[ch], s0);
      s1 = MFMAF16(kh1, qh[ch], s1);
    }
    __builtin_amdgcn_s_setprio(0);

    // ---- online softmax over m (lane holds 8 m-values of one n-column)
    float tmax = fmaxf(fmaxf(fmaxf(s0[0],s0[1]), fmaxf(s0[2],s0[3])),
                       fmaxf(fmaxf(s1[0],s1[1]), fmaxf(s1[2],s1[3])));
    tmax = fmaxf(tmax, __shfl_xor(tmax, 16));
    tmax = fmaxf(tmax, __shfl_xor(tmax, 32));

    if (__any(tmax > mst)){
      float mn = fmaxf(mst, tmax);
      float sc = exp2_fast((mst - mn) * LOG2E);
      lst *= sc;
      #pragma unroll
      for (int i = 0; i < 16; i++){
        o_acc[i][0]*=sc; o_acc[i][1]*=sc; o_acc[i][2]*=sc; o_acc[i][3]*=sc;
      }
      mst = mn;
    }
    const float mb = mst * LOG2E;
    float p0 = exp2_fast(s0[0]*LOG2E - mb);
    float p1 = exp2_fast(s0[1]*LOG2E - mb);
    float p2 = exp2_fast(s0[2]*LOG2E - mb);
    float p3 = exp2_fast(s0[3]*LOG2E - mb);
    float p4 = exp2_fast(s1[0]*LOG2E - mb);
    float p5 = exp2_fast(s1[1]*LOG2E - mb);
    float p6 = exp2_fast(s1[2]*LOG2E - mb);
    float p7 = exp2_fast(s1[3]*LOG2E - mb);

    float psum = ((p0+p1)+(p2+p3)) + ((p4+p5)+(p6+p7));
    psum += __shfl_xor(psum, 16);
    psum += __shfl_xor(psum, 32);
    lst  += psum;

    // ---- P -> PV B-fragment: pack f16 pairs, cross-group transpose via shfl
    int W0 = pk_f16(p0, p1);
    int W1 = pk_f16(p2, p3);
    int W2 = pk_f16(p4, p5);
    int W3 = pk_f16(p6, p7);

    int a0 = __shfl(W0, laneA), a1 = __shfl(W1, laneA);
    int a2 = __shfl(W2, laneA), a3 = __shfl(W3, laneA);
    int b0 = __shfl(W0, laneB), b1 = __shfl(W1, laneB);
    int b2 = __shfl(W2, laneB), b3 = __shfl(W3, laneB);
    int4v ti;
    ti[0] = selLow ? a0 : a2;
    ti[1] = selLow ? a1 : a3;
    ti[2] = selLow ? b0 : b2;
    ti[3] = selLow ? b1 : b3;
    short8 pf = __builtin_bit_cast(short8, ti);   // P[n][m = g*8 + j]

    // ---- PV: O^T[c][n] += sum_m V[m,c] P[n,m]
    __builtin_amdgcn_s_setprio(1);
    #pragma unroll
    for (int ct = 0; ct < 16; ct++){
      short8 vf = *(const short8*)(vbuf + ct*1024 + vb);
      o_acc[ct] = MFMAF16(vf, pf, o_acc[ct]);
    }
    __builtin_amdgcn_s_setprio(0);

    buf ^= 1;
  }

  // ---- epilogue: unnormalized partials (f16) + (m,l)
  const size_t pbase = ((((size_t)(hf*4 + b))*32 + qt)*128 + (w*16 + col)) * 256;
  #pragma unroll
  for (int ct = 0; ct < 16; ct++){
    int2v pkd = { pk_f16(o_acc[ct][0], o_acc[ct][1]),
                  pk_f16(o_acc[ct][2], o_acc[ct][3]) };
    *(int2v*)&part[pbase + ct*16 + g*4] = pkd;
  }
  if (lane < 16){
    size_t mb2 = ((((size_t)(hf*4 + b))*32 + qt)*128 + w*16 + col)*2;
    mlbuf[mb2]     = mst;
    mlbuf[mb2 + 1] = lst;
  }
}

// ---------------------------------------------------------------- merge halves
// thread: one (c, b, 8-n chunk); reads strided f16 partials (L2-hot),
// writes out[b,c,n] coalesced.
__global__ __launch_bounds__(256) void merge_kernel(
    const unsigned short* __restrict__ part, const float* __restrict__ mlbuf,
    float* __restrict__ out)
{
  const int T  = blockIdx.x*256 + threadIdx.x;   // 524288
  const int c  = T >> 11;
  const int r  = T & 2047;
  const int b  = r >> 9;
  const int n8 = (r & 511) * 8;
  const int qt = n8 >> 7, q0 = n8 & 127;

  const size_t iA = (((size_t)b)*32 + qt)*128 + q0;          // hf=0
  const size_t iB = (((size_t)(4 + b))*32 + qt)*128 + q0;    // hf=1

  f32x4 o0, o1;
  #pragma unroll
  for (int j = 0; j < 8; j++){
    float mA = mlbuf[(iA+j)*2], lA = mlbuf[(iA+j)*2+1];
    float mB = mlbuf[(iB+j)*2], lB = mlbuf[(iB+j)*2+1];
    float m  = fmaxf(mA, mB);
    float sa = exp2_fast((mA - m) * LOG2E);
    float sb = exp2_fast((mB - m) * LOG2E);
    float rl = 1.0f / (lA*sa + lB*sb);
    float pA = (float)*(const _Float16*)&part[(iA+j)*256 + c];
    float pB = (float)*(const _Float16*)&part[(iB+j)*256 + c];
    float v  = (pA*sa + pB*sb) * rl;
    if (j < 4) o0[j] = v; else o1[j-4] = v;
  }
  float* op = out + ((size_t)(b*256 + c))*4096 + n8;
  *(f32x4*)op       = o0;
  *(f32x4*)(op + 4) = o1;
}

// ---------------------------------------------------------------- launch
extern "C" void kernel_launch(void* const* d_in, const int* in_sizes, int n_in,
                              void* d_out, int out_size, void* d_ws, size_t ws_size,
                              hipStream_t stream)
{
  const float* x  = (const float*)d_in[0];
  const float* y  = (const float*)d_in[1];
  const float* Wq = (const float*)d_in[2];
  const float* bq = (const float*)d_in[3];
  const float* Wk = (const float*)d_in[4];
  const float* bk = (const float*)d_in[5];
  const float* Wv = (const float*)d_in[6];
  const float* bv = (const float*)d_in[7];
  float* out = (float*)d_out;

  char* ws = (char*)d_ws;
  const size_t MB = 1048576;
  unsigned short* qf   = (unsigned short*)(ws + 0*MB);
  unsigned short* kfp  = (unsigned short*)(ws + 8*MB);
  unsigned short* vtf  = (unsigned short*)(ws + 16*MB);
  unsigned short* wf   = (unsigned short*)(ws + 24*MB);
  unsigned short* part = (unsigned short*)(ws + 24*MB + 393216);
  float*          mlb  = (float*)(ws + 24*MB + 393216 + 16777216);

  cvt_w<<<dim3(256,3), dim3(256), 0, stream>>>(Wq, Wk, Wv, wf);
  proj_kernel<<<dim3(64,4,3), dim3(256), 0, stream>>>(x, y, wf, bq, bk, bv,
                                                      qf, kfp, vtf);
  attn_kernel<<<dim3(256), dim3(512), 0, stream>>>(qf, kfp, vtf, part, mlb);
  merge_kernel<<<dim3(2048), dim3(256), 0, stream>>>(part, mlb, out);
}

// Round 9
// 222.185 us; speedup vs baseline: 1.5543x; 1.1553x over previous
//
#include <hip/hip_runtime.h>

// CrossAttention: B=4, C=256, H=W=64, N=4096, fp32 in/out.
// ws: qf 0 (8MB), kf 8MB, vtf 16MB, wf 24MB (384KB),
//     part @25559040 (nsplit x 8MB f16), ml after part (nsplit x 128KB f32).

typedef __attribute__((ext_vector_type(8))) short short8;
typedef __attribute__((ext_vector_type(4))) float f32x4;
typedef __attribute__((ext_vector_type(4))) int int4v;
typedef __attribute__((ext_vector_type(2))) int int2v;
typedef __attribute__((ext_vector_type(8))) _Float16 half8;

#define LOG2E 1.44269504089f

static __device__ __forceinline__ float exp2_fast(float x){ return __builtin_amdgcn_exp2f(x); }

static __device__ __forceinline__ int pk_f16(float a, float b){
  auto h = __builtin_amdgcn_cvt_pkrtz(a, b);   // low=a, high=b
  return __builtin_bit_cast(int, h);
}
static __device__ __forceinline__ unsigned short f2h(float v){
  return __builtin_bit_cast(unsigned short, (_Float16)v);
}

#define GLOAD16(gp, lp) __builtin_amdgcn_global_load_lds( \
  (const __attribute__((address_space(1))) void*)(gp),    \
  (__attribute__((address_space(3))) void*)(lp), 16, 0, 0)

#define MFMAF16(a,b,c) __builtin_amdgcn_mfma_f32_16x16x32_f16( \
  __builtin_bit_cast(half8, a), __builtin_bit_cast(half8, b), c, 0, 0, 0)

// ---------------------------------------------------------------- W -> f16
__global__ __launch_bounds__(256) void cvt_w(
    const float* __restrict__ wq, const float* __restrict__ wk,
    const float* __restrict__ wv, unsigned short* __restrict__ wf)
{
  const int o = blockIdx.x, t = blockIdx.y, c = threadIdx.x;
  const float* w = (t == 0) ? wq : ((t == 1) ? wk : wv);
  wf[t*65536 + o*256 + c] = f2h(w[o*256 + c]);
}

// ---------------------------------------------------------------- projections (f16 MFMA)
__global__ __launch_bounds__(256, 2) void proj_kernel(
    const float* __restrict__ x, const float* __restrict__ y,
    const unsigned short* __restrict__ wf,
    const float* __restrict__ bq, const float* __restrict__ bk, const float* __restrict__ bv,
    unsigned short* __restrict__ qf, unsigned short* __restrict__ kf,
    unsigned short* __restrict__ vtf)
{
  __shared__ float xs[256*64];       // 64KB
  __shared__ short wlds[2][4096];    // 2 x 8KB W tiles

  const int t   = blockIdx.z;
  const int b   = blockIdx.y;
  const int n0  = blockIdx.x * 64;
  const int tid = threadIdx.x;
  const int w   = tid >> 6, lane = tid & 63, g = lane >> 4, l15 = lane & 15;

  const float* src = ((t == 0) ? x : y) + (size_t)b*1048576 + n0;
  const char*  wt_b = (const char*)(wf + t*65536);

  int wsrc[2];
  #pragma unroll
  for (int i = 0; i < 2; i++){
    int s = w*2 + i;
    int row = s*2 + (lane >> 5);
    wsrc[i] = row*512 + (((lane & 31)*16) ^ ((row & 7) << 4));
  }

  #pragma unroll
  for (int i = 0; i < 16; i++){
    int c  = i*16 + (tid >> 4);
    int gg = (c >> 3) & 3;
    int sg = ((tid & 15) - 4*gg) & 15;
    GLOAD16((const char*)src + (size_t)c*16384 + sg*16,
            (char*)xs + (i*256 + tid)*16);
  }
  #pragma unroll
  for (int i = 0; i < 2; i++){
    int s = w*2 + i;
    GLOAD16(wt_b + wsrc[i], (char*)&wlds[0][0] + s*1024);
  }
  __syncthreads();

  int4v xf[8];
  {
    const int nn = (w*16 + l15 + 16*g) & 63;
    #pragma unroll
    for (int cs = 0; cs < 8; cs++){
      float v[8];
      #pragma unroll
      for (int j = 0; j < 8; j++) v[j] = xs[(cs*32 + g*8 + j)*64 + nn];
      int4v f;
      f[0] = pk_f16(v[0], v[1]); f[1] = pk_f16(v[2], v[3]);
      f[2] = pk_f16(v[4], v[5]); f[3] = pk_f16(v[6], v[7]);
      xf[cs] = f;
    }
  }

  const float* bias = (t == 0) ? bq : ((t == 1) ? bk : bv);

  int buf = 0;
  for (int ot = 0; ot < 16; ot++){
    if (ot < 15){
      #pragma unroll
      for (int i = 0; i < 2; i++){
        int s = w*2 + i;
        GLOAD16(wt_b + (ot+1)*8192 + wsrc[i], (char*)&wlds[buf^1][0] + s*1024);
      }
    }

    f32x4 acc;
    if (t < 2){
      float bo = bias[ot*16 + l15];
      acc = (f32x4){bo, bo, bo, bo};
    } else {
      acc = *(const f32x4*)&bias[ot*16 + g*4];
    }
    const char* wb = (const char*)&wlds[buf][0];
    #pragma unroll
    for (int cs = 0; cs < 8; cs++){
      short8 wfr = *(const short8*)(wb + (l15*512 + ((cs*64 + g*16) ^ ((l15 & 7) << 4))));
      if (t < 2) acc = MFMAF16(__builtin_bit_cast(short8, xf[cs]), wfr, acc);  // D[n][o]
      else       acc = MFMAF16(wfr, __builtin_bit_cast(short8, xf[cs]), acc);  // D[o][n]
    }
    if (t < 2){
      unsigned short* outp = (t == 0) ? qf : kf;
      #pragma unroll
      for (int r = 0; r < 4; r++){
        int n = n0 + w*16 + g*4 + r;
        outp[((size_t)(b*4096 + n))*256 + ot*16 + l15] = f2h(acc[r]);
      }
    } else {
      #pragma unroll
      for (int r = 0; r < 4; r++){
        int o = ot*16 + g*4 + r;
        vtf[((size_t)(b*256 + o))*4096 + n0 + w*16 + l15] = f2h(acc[r]);
      }
    }
    __syncthreads();
    buf ^= 1;
  }
}

// ---------------------------------------------------------------- attention (partials)
// Block: 8 waves x 32 q-rows (two 16-row frags) = 256 q-rows; one KV split
// stream of 4096/nsplit rows, KVBLK=32, TRIPLE-buffered LDS (96KB) with
// counted vmcnt(4) — prefetch issued pre-barrier, never drained to 0 in-loop.
// Each K/V read feeds 2 MFMAs (0.5 reads/MFMA vs 0.75 before).
__global__ __launch_bounds__(512, 2) void attn_kernel(
    const unsigned short* __restrict__ qf, const unsigned short* __restrict__ kf,
    const unsigned short* __restrict__ vtf,
    unsigned short* __restrict__ part, float* __restrict__ mlbuf,
    int nsplit, int iters)
{
  __shared__ short k_s[3*32*256];   // [buf][m][c], rows 512B, swz ^((m&7)<<4)
  __shared__ short v_s[3*256*32];   // [buf][c][m], rows 64B,  swz ^(((c>>1)&3)<<4)

  const int tid  = threadIdx.x;
  const int w    = tid >> 6, lane = tid & 63, g = lane >> 4, col = lane & 15;
  const int bid  = blockIdx.x;

  int b, kvq, qt;
  if (nsplit == 4){
    int xcd = bid & 7, s = bid >> 3;
    int combo = xcd*2 + (s >> 4);        // blocks sharing (b,kvq) on same XCD
    qt = s & 15;  b = combo >> 2;  kvq = combo & 3;
  } else {
    int combo = bid & 7;
    qt = bid >> 3;  b = combo >> 1;  kvq = combo & 1;
  }
  const int qbase = qt * 256;

  // Q fragments: nn in {0,1}; n = qbase + w*32 + nn*16 + col
  short8 qh[2][8];
  #pragma unroll
  for (int nn = 0; nn < 2; nn++){
    const size_t qoff = ((size_t)(b*4096 + qbase + w*32 + nn*16 + col))*256 + g*8;
    #pragma unroll
    for (int ch = 0; ch < 8; ch++)
      qh[nn][ch] = *(const short8*)(qf + qoff + ch*32);
  }

  f32x4 o_acc[2][16];
  #pragma unroll
  for (int nn = 0; nn < 2; nn++)
    #pragma unroll
    for (int i = 0; i < 16; i++){
      o_acc[nn][i][0]=0.f; o_acc[nn][i][1]=0.f; o_acc[nn][i][2]=0.f; o_acc[nn][i][3]=0.f;
    }
  float mst[2] = {-1e30f, -1e30f};
  float lst[2] = {0.f, 0.f};

  const int swzK = (col & 7) << 4;
  const int g16  = g << 4;
  const int kb0  = col * 512;
  const int kb1  = kb0 + 8192;
  const int vb   = col*64 + (g16 ^ (((col>>1)&3)<<4));

  const int laneA  = col + ((g & 1) ? 32 : 0);
  const int laneB  = laneA + 16;
  const bool selLow = (g < 2);

  // staging source offsets (pre-swizzled; 2 K segs + 2 V segs per wave)
  int ksrc[2], vsrc[2];
  #pragma unroll
  for (int i = 0; i < 2; i++){
    int s = w*2 + i;
    int m = s*2 + (lane >> 5);
    ksrc[i] = m*512 + (((lane & 31)*16) ^ ((m & 7) << 4));
    int c = s*16 + (lane >> 2);
    vsrc[i] = c*8192 + (((lane & 3)*16) ^ (((lane >> 3) & 3) << 4));
  }

  const int rows = 4096 / nsplit;
  const char* khg = (const char*)(kf + ((size_t)b*4096 + kvq*rows)*256);
  const char* vg  = (const char*)(vtf + ((size_t)b*256)*4096) + kvq*rows*2;

  // prologue: stage tile 0 into buf 0
  #pragma unroll
  for (int i = 0; i < 2; i++){
    int s = w*2 + i;
    GLOAD16(khg + ksrc[i], (char*)k_s + s*1024);
    GLOAD16(vg  + vsrc[i], (char*)v_s + s*1024);
  }

  int cur = 0, nxt = 1;
  for (int it = 0; it < iters; ++it){
    if (it + 1 < iters){
      // prefetch tile it+1 into buf nxt BEFORE the wait (stays in flight)
      const char* kht = khg + (size_t)(it+1)*16384;
      const char* vtt = vg  + (size_t)(it+1)*64;
      const int ko = nxt*16384, vo = nxt*16384;
      #pragma unroll
      for (int i = 0; i < 2; i++){
        int s = w*2 + i;
        GLOAD16(kht + ksrc[i], (char*)k_s + ko + s*1024);
        GLOAD16(vtt + vsrc[i], (char*)v_s + vo + s*1024);
      }
      asm volatile("s_waitcnt vmcnt(4)" ::: "memory");   // tile `it` landed
    } else {
      asm volatile("s_waitcnt vmcnt(0)" ::: "memory");
    }
    __builtin_amdgcn_s_barrier();
    __builtin_amdgcn_sched_barrier(0);

    const char* kb   = (const char*)k_s + cur*16384;
    const char* vbuf = (const char*)v_s + cur*16384;

    // ---- QK^T (swapped): S^T[m][n]; K read shared by both q-frags
    f32x4 s00 = {0.f,0.f,0.f,0.f}, s01 = {0.f,0.f,0.f,0.f};
    f32x4 s10 = {0.f,0.f,0.f,0.f}, s11 = {0.f,0.f,0.f,0.f};
    __builtin_amdgcn_s_setprio(1);
    #pragma unroll
    for (int ch = 0; ch < 8; ch++){
      int inr = ((ch << 6) | g16) ^ swzK;
      short8 kh0 = *(const short8*)(kb + kb0 + inr);
      short8 kh1 = *(const short8*)(kb + kb1 + inr);
      s00 = MFMAF16(kh0, qh[0][ch], s00);
      s01 = MFMAF16(kh1, qh[0][ch], s01);
      s10 = MFMAF16(kh0, qh[1][ch], s10);
      s11 = MFMAF16(kh1, qh[1][ch], s11);
    }
    __builtin_amdgcn_s_setprio(0);

    // ---- online softmax + P-frag per nn
    short8 pf[2];
    #pragma unroll
    for (int nn = 0; nn < 2; nn++){
      f32x4 s0 = nn ? s10 : s00;
      f32x4 s1 = nn ? s11 : s01;
      float tmax = fmaxf(fmaxf(fmaxf(s0[0],s0[1]), fmaxf(s0[2],s0[3])),
                         fmaxf(fmaxf(s1[0],s1[1]), fmaxf(s1[2],s1[3])));
      tmax = fmaxf(tmax, __shfl_xor(tmax, 16));
      tmax = fmaxf(tmax, __shfl_xor(tmax, 32));

      if (__any(tmax > mst[nn])){
        float mn = fmaxf(mst[nn], tmax);
        float sc = exp2_fast((mst[nn] - mn) * LOG2E);
        lst[nn] *= sc;
        #pragma unroll
        for (int i = 0; i < 16; i++){
          o_acc[nn][i][0]*=sc; o_acc[nn][i][1]*=sc;
          o_acc[nn][i][2]*=sc; o_acc[nn][i][3]*=sc;
        }
        mst[nn] = mn;
      }
      const float mb = mst[nn] * LOG2E;
      float p0 = exp2_fast(s0[0]*LOG2E - mb);
      float p1 = exp2_fast(s0[1]*LOG2E - mb);
      float p2 = exp2_fast(s0[2]*LOG2E - mb);
      float p3 = exp2_fast(s0[3]*LOG2E - mb);
      float p4 = exp2_fast(s1[0]*LOG2E - mb);
      float p5 = exp2_fast(s1[1]*LOG2E - mb);
      float p6 = exp2_fast(s1[2]*LOG2E - mb);
      float p7 = exp2_fast(s1[3]*LOG2E - mb);

      float psum = ((p0+p1)+(p2+p3)) + ((p4+p5)+(p6+p7));
      psum += __shfl_xor(psum, 16);
      psum += __shfl_xor(psum, 32);
      lst[nn] += psum;

      int W0 = pk_f16(p0, p1);
      int W1 = pk_f16(p2, p3);
      int W2 = pk_f16(p4, p5);
      int W3 = pk_f16(p6, p7);

      int a0 = __shfl(W0, laneA), a1 = __shfl(W1, laneA);
      int a2 = __shfl(W2, laneA), a3 = __shfl(W3, laneA);
      int b0 = __shfl(W0, laneB), b1 = __shfl(W1, laneB);
      int b2 = __shfl(W2, laneB), b3 = __shfl(W3, laneB);
      int4v ti;
      ti[0] = selLow ? a0 : a2;
      ti[1] = selLow ? a1 : a3;
      ti[2] = selLow ? b0 : b2;
      ti[3] = selLow ? b1 : b3;
      pf[nn] = __builtin_bit_cast(short8, ti);   // P[n][m = g*8 + j]
    }

    // ---- PV: O^T[c][n] += sum_m V[m,c] P[n,m]; V read shared by both nn
    __builtin_amdgcn_s_setprio(1);
    #pragma unroll
    for (int ct = 0; ct < 16; ct++){
      short8 vf = *(const short8*)(vbuf + ct*1024 + vb);
      o_acc[0][ct] = MFMAF16(vf, pf[0], o_acc[0][ct]);
      o_acc[1][ct] = MFMAF16(vf, pf[1], o_acc[1][ct]);
    }
    __builtin_amdgcn_s_setprio(0);

    cur = nxt;
    nxt = (nxt + 1 == 3) ? 0 : nxt + 1;
  }

  // ---- epilogue: unnormalized f16 partials + (m,l)
  const int s4b = kvq*4 + b;
  #pragma unroll
  for (int nn = 0; nn < 2; nn++){
    const int n = qbase + w*32 + nn*16 + col;
    const size_t pbase = ((size_t)s4b*4096 + n)*256;
    #pragma unroll
    for (int ct = 0; ct < 16; ct++){
      int2v pkd = { pk_f16(o_acc[nn][ct][0], o_acc[nn][ct][1]),
                    pk_f16(o_acc[nn][ct][2], o_acc[nn][ct][3]) };
      *(int2v*)&part[pbase + ct*16 + g*4] = pkd;
    }
    if (g == 0){
      const size_t mb2 = ((size_t)s4b*4096 + n)*2;
      mlbuf[mb2]     = mst[nn];
      mlbuf[mb2 + 1] = lst[nn];
    }
  }
}

// ---------------------------------------------------------------- merge splits
__global__ __launch_bounds__(256) void merge_kernel(
    const unsigned short* __restrict__ part, const float* __restrict__ mlbuf,
    float* __restrict__ out, int nsplit)
{
  const int T  = blockIdx.x*256 + threadIdx.x;   // 524288
  const int c  = T >> 11;
  const int r  = T & 2047;
  const int b  = r >> 9;
  const int n8 = (r & 511) * 8;

  f32x4 o0, o1;
  #pragma unroll
  for (int j = 0; j < 8; j++){
    const int n = n8 + j;
    float m = -1e30f, num = 0.f, den = 0.f;
    for (int s = 0; s < nsplit; s++){
      const size_t idx = (size_t)(s*4 + b)*4096 + n;
      float ms = mlbuf[idx*2], ls = mlbuf[idx*2 + 1];
      float ps = (float)*(const _Float16*)&part[idx*256 + c];
      float mn = fmaxf(m, ms);
      float sa = exp2_fast((m  - mn) * LOG2E);
      float sb = exp2_fast((ms - mn) * LOG2E);
      num = num*sa + ps*sb;
      den = den*sa + ls*sb;
      m = mn;
    }
    float v = num / den;
    if (j < 4) o0[j] = v; else o1[j-4] = v;
  }
  float* op = out + ((size_t)(b*256 + c))*4096 + n8;
  *(f32x4*)op       = o0;
  *(f32x4*)(op + 4) = o1;
}

// ---------------------------------------------------------------- launch
extern "C" void kernel_launch(void* const* d_in, const int* in_sizes, int n_in,
                              void* d_out, int out_size, void* d_ws, size_t ws_size,
                              hipStream_t stream)
{
  const float* x  = (const float*)d_in[0];
  const float* y  = (const float*)d_in[1];
  const float* Wq = (const float*)d_in[2];
  const float* bq = (const float*)d_in[3];
  const float* Wk = (const float*)d_in[4];
  const float* bk = (const float*)d_in[5];
  const float* Wv = (const float*)d_in[6];
  const float* bv = (const float*)d_in[7];
  float* out = (float*)d_out;

  char* ws = (char*)d_ws;
  const size_t MB = 1048576;
  unsigned short* qf   = (unsigned short*)(ws + 0*MB);
  unsigned short* kfp  = (unsigned short*)(ws + 8*MB);
  unsigned short* vtf  = (unsigned short*)(ws + 16*MB);
  unsigned short* wf   = (unsigned short*)(ws + 24*MB);
  unsigned short* part = (unsigned short*)(ws + 24*MB + 393216);

  // 4-way KV split needs ~59.7MB of ws; fall back to 2-way otherwise.
  const int nsplit = (ws_size >= 61*MB) ? 4 : 2;
  const int iters  = (4096 / nsplit) / 32;
  float* mlb = (float*)(ws + 24*MB + 393216 + (size_t)nsplit*8*MB);

  cvt_w<<<dim3(256,3), dim3(256), 0, stream>>>(Wq, Wk, Wv, wf);
  proj_kernel<<<dim3(64,4,3), dim3(256), 0, stream>>>(x, y, wf, bq, bk, bv,
                                                      qf, kfp, vtf);
  attn_kernel<<<dim3(64*nsplit), dim3(512), 0, stream>>>(qf, kfp, vtf, part, mlb,
                                                         nsplit, iters);
  merge_kernel<<<dim3(2048), dim3(256), 0, stream>>>(part, mlb, out, nsplit);
}

// Round 10
// 159.738 us; speedup vs baseline: 2.1620x; 1.3909x over previous
//
#include <hip/hip_runtime.h>

// CrossAttention: B=4, C=256, H=W=64, N=4096, fp32 in/out.
// ws: qf 0 (8MB), kf 8MB, vtf 16MB, wf 24MB (384KB),
//     part f16 @24MB+384KB ((nsplit-1) x 8MB, [c][n] planes), ml f32 after.
// Split 0 partials (f32) live in d_out itself (final [b][c][n] layout).

typedef __attribute__((ext_vector_type(8))) short short8;
typedef __attribute__((ext_vector_type(4))) float f32x4;
typedef __attribute__((ext_vector_type(4))) int int4v;
typedef __attribute__((ext_vector_type(8))) _Float16 half8;

#define LOG2E 1.44269504089f

static __device__ __forceinline__ float exp2_fast(float x){ return __builtin_amdgcn_exp2f(x); }

static __device__ __forceinline__ int pk_f16(float a, float b){
  auto h = __builtin_amdgcn_cvt_pkrtz(a, b);   // low=a, high=b
  return __builtin_bit_cast(int, h);
}
static __device__ __forceinline__ unsigned short f2h(float v){
  return __builtin_bit_cast(unsigned short, (_Float16)v);
}

#define GLOAD16(gp, lp) __builtin_amdgcn_global_load_lds( \
  (const __attribute__((address_space(1))) void*)(gp),    \
  (__attribute__((address_space(3))) void*)(lp), 16, 0, 0)

#define MFMAF16(a,b,c) __builtin_amdgcn_mfma_f32_16x16x32_f16( \
  __builtin_bit_cast(half8, a), __builtin_bit_cast(half8, b), c, 0, 0, 0)

// ---------------------------------------------------------------- W -> f16
__global__ __launch_bounds__(256) void cvt_w(
    const float* __restrict__ wq, const float* __restrict__ wk,
    const float* __restrict__ wv, unsigned short* __restrict__ wf)
{
  const int o = blockIdx.x, t = blockIdx.y, c = threadIdx.x;
  const float* w = (t == 0) ? wq : ((t == 1) ? wk : wv);
  wf[t*65536 + o*256 + c] = f2h(w[o*256 + c]);
}

// ---------------------------------------------------------------- projections (f16 MFMA)
__global__ __launch_bounds__(256, 2) void proj_kernel(
    const float* __restrict__ x, const float* __restrict__ y,
    const unsigned short* __restrict__ wf,
    const float* __restrict__ bq, const float* __restrict__ bk, const float* __restrict__ bv,
    unsigned short* __restrict__ qf, unsigned short* __restrict__ kf,
    unsigned short* __restrict__ vtf)
{
  __shared__ float xs[256*64];       // 64KB
  __shared__ short wlds[2][4096];    // 2 x 8KB W tiles

  const int t   = blockIdx.z;
  const int b   = blockIdx.y;
  const int n0  = blockIdx.x * 64;
  const int tid = threadIdx.x;
  const int w   = tid >> 6, lane = tid & 63, g = lane >> 4, l15 = lane & 15;

  const float* src = ((t == 0) ? x : y) + (size_t)b*1048576 + n0;
  const char*  wt_b = (const char*)(wf + t*65536);

  int wsrc[2];
  #pragma unroll
  for (int i = 0; i < 2; i++){
    int s = w*2 + i;
    int row = s*2 + (lane >> 5);
    wsrc[i] = row*512 + (((lane & 31)*16) ^ ((row & 7) << 4));
  }

  #pragma unroll
  for (int i = 0; i < 16; i++){
    int c  = i*16 + (tid >> 4);
    int gg = (c >> 3) & 3;
    int sg = ((tid & 15) - 4*gg) & 15;
    GLOAD16((const char*)src + (size_t)c*16384 + sg*16,
            (char*)xs + (i*256 + tid)*16);
  }
  #pragma unroll
  for (int i = 0; i < 2; i++){
    int s = w*2 + i;
    GLOAD16(wt_b + wsrc[i], (char*)&wlds[0][0] + s*1024);
  }
  __syncthreads();

  int4v xf[8];
  {
    const int nn = (w*16 + l15 + 16*g) & 63;
    #pragma unroll
    for (int cs = 0; cs < 8; cs++){
      float v[8];
      #pragma unroll
      for (int j = 0; j < 8; j++) v[j] = xs[(cs*32 + g*8 + j)*64 + nn];
      int4v f;
      f[0] = pk_f16(v[0], v[1]); f[1] = pk_f16(v[2], v[3]);
      f[2] = pk_f16(v[4], v[5]); f[3] = pk_f16(v[6], v[7]);
      xf[cs] = f;
    }
  }

  const float* bias = (t == 0) ? bq : ((t == 1) ? bk : bv);

  int buf = 0;
  for (int ot = 0; ot < 16; ot++){
    if (ot < 15){
      #pragma unroll
      for (int i = 0; i < 2; i++){
        int s = w*2 + i;
        GLOAD16(wt_b + (ot+1)*8192 + wsrc[i], (char*)&wlds[buf^1][0] + s*1024);
      }
    }

    f32x4 acc;
    if (t < 2){
      float bo = bias[ot*16 + l15];
      acc = (f32x4){bo, bo, bo, bo};
    } else {
      acc = *(const f32x4*)&bias[ot*16 + g*4];
    }
    const char* wb = (const char*)&wlds[buf][0];
    #pragma unroll
    for (int cs = 0; cs < 8; cs++){
      short8 wfr = *(const short8*)(wb + (l15*512 + ((cs*64 + g*16) ^ ((l15 & 7) << 4))));
      if (t < 2) acc = MFMAF16(__builtin_bit_cast(short8, xf[cs]), wfr, acc);  // D[n][o]
      else       acc = MFMAF16(wfr, __builtin_bit_cast(short8, xf[cs]), acc);  // D[o][n]
    }
    if (t < 2){
      unsigned short* outp = (t == 0) ? qf : kf;
      #pragma unroll
      for (int r = 0; r < 4; r++){
        int n = n0 + w*16 + g*4 + r;
        outp[((size_t)(b*4096 + n))*256 + ot*16 + l15] = f2h(acc[r]);
      }
    } else {
      #pragma unroll
      for (int r = 0; r < 4; r++){
        int o = ot*16 + g*4 + r;
        vtf[((size_t)(b*256 + o))*4096 + n0 + w*16 + l15] = f2h(acc[r]);
      }
    }
    __syncthreads();
    buf ^= 1;
  }
}

// ---------------------------------------------------------------- attention (partials)
// Block: 8 waves x 32 q-rows = 256 q-rows; one KV split stream of 4096/nsplit
// rows, KVBLK=32, triple-buffered LDS (96KB), counted vmcnt(4).
// Split 0 -> f32 partials in d_out ([b][c][n]); splits >=1 -> f16 [c][n] planes.
__global__ __launch_bounds__(512, 2) void attn_kernel(
    const unsigned short* __restrict__ qf, const unsigned short* __restrict__ kf,
    const unsigned short* __restrict__ vtf,
    float* __restrict__ outp, unsigned short* __restrict__ part,
    float* __restrict__ mlbuf, int nsplit, int iters)
{
  __shared__ short k_s[3*32*256];   // [buf][m][c], rows 512B, swz ^((m&7)<<4)
  __shared__ short v_s[3*256*32];   // [buf][c][m], rows 64B,  swz ^(((c>>1)&3)<<4)

  const int tid  = threadIdx.x;
  const int w    = tid >> 6, lane = tid & 63, g = lane >> 4, col = lane & 15;
  const int bid  = blockIdx.x;

  int b, kvq, qt;
  if (nsplit == 4){
    int xcd = bid & 7, s = bid >> 3;
    int combo = xcd*2 + (s >> 4);        // 16 qt-blocks sharing (b,kvq) per XCD-pair
    qt = s & 15;  b = combo >> 2;  kvq = combo & 3;
  } else {
    int combo = bid & 7;
    qt = bid >> 3;  b = combo >> 1;  kvq = combo & 1;
  }
  const int qbase = qt * 256;

  // Q fragments: nn in {0,1}; n = qbase + w*32 + nn*16 + col
  short8 qh[2][8];
  #pragma unroll
  for (int nn = 0; nn < 2; nn++){
    const size_t qoff = ((size_t)(b*4096 + qbase + w*32 + nn*16 + col))*256 + g*8;
    #pragma unroll
    for (int ch = 0; ch < 8; ch++)
      qh[nn][ch] = *(const short8*)(qf + qoff + ch*32);
  }

  f32x4 o_acc[2][16];
  #pragma unroll
  for (int nn = 0; nn < 2; nn++)
    #pragma unroll
    for (int i = 0; i < 16; i++){
      o_acc[nn][i][0]=0.f; o_acc[nn][i][1]=0.f; o_acc[nn][i][2]=0.f; o_acc[nn][i][3]=0.f;
    }
  float mst[2] = {-1e30f, -1e30f};
  float lst[2] = {0.f, 0.f};

  const int swzK = (col & 7) << 4;
  const int g16  = g << 4;
  const int kb0  = col * 512;
  const int kb1  = kb0 + 8192;
  const int vb   = col*64 + (g16 ^ (((col>>1)&3)<<4));

  const int laneA  = col + ((g & 1) ? 32 : 0);
  const int laneB  = laneA + 16;
  const bool selLow = (g < 2);

  int ksrc[2], vsrc[2];
  #pragma unroll
  for (int i = 0; i < 2; i++){
    int s = w*2 + i;
    int m = s*2 + (lane >> 5);
    ksrc[i] = m*512 + (((lane & 31)*16) ^ ((m & 7) << 4));
    int c = s*16 + (lane >> 2);
    vsrc[i] = c*8192 + (((lane & 3)*16) ^ (((lane >> 3) & 3) << 4));
  }

  const int rows = 4096 / nsplit;
  const char* khg = (const char*)(kf + ((size_t)b*4096 + kvq*rows)*256);
  const char* vg  = (const char*)(vtf + ((size_t)b*256)*4096) + kvq*rows*2;

  #pragma unroll
  for (int i = 0; i < 2; i++){
    int s = w*2 + i;
    GLOAD16(khg + ksrc[i], (char*)k_s + s*1024);
    GLOAD16(vg  + vsrc[i], (char*)v_s + s*1024);
  }

  int cur = 0, nxt = 1;
  for (int it = 0; it < iters; ++it){
    if (it + 1 < iters){
      const char* kht = khg + (size_t)(it+1)*16384;
      const char* vtt = vg  + (size_t)(it+1)*64;
      const int ko = nxt*16384, vo = nxt*16384;
      #pragma unroll
      for (int i = 0; i < 2; i++){
        int s = w*2 + i;
        GLOAD16(kht + ksrc[i], (char*)k_s + ko + s*1024);
        GLOAD16(vtt + vsrc[i], (char*)v_s + vo + s*1024);
      }
      asm volatile("s_waitcnt vmcnt(4)" ::: "memory");   // tile `it` landed
    } else {
      asm volatile("s_waitcnt vmcnt(0)" ::: "memory");
    }
    __builtin_amdgcn_s_barrier();
    __builtin_amdgcn_sched_barrier(0);

    const char* kb   = (const char*)k_s + cur*16384;
    const char* vbuf = (const char*)v_s + cur*16384;

    // ---- QK^T (swapped): K read shared by both q-frags
    f32x4 s00 = {0.f,0.f,0.f,0.f}, s01 = {0.f,0.f,0.f,0.f};
    f32x4 s10 = {0.f,0.f,0.f,0.f}, s11 = {0.f,0.f,0.f,0.f};
    __builtin_amdgcn_s_setprio(1);
    #pragma unroll
    for (int ch = 0; ch < 8; ch++){
      int inr = ((ch << 6) | g16) ^ swzK;
      short8 kh0 = *(const short8*)(kb + kb0 + inr);
      short8 kh1 = *(const short8*)(kb + kb1 + inr);
      s00 = MFMAF16(kh0, qh[0][ch], s00);
      s01 = MFMAF16(kh1, qh[0][ch], s01);
      s10 = MFMAF16(kh0, qh[1][ch], s10);
      s11 = MFMAF16(kh1, qh[1][ch], s11);
    }
    __builtin_amdgcn_s_setprio(0);

    // ---- online softmax + P-frag per nn
    short8 pf[2];
    #pragma unroll
    for (int nn = 0; nn < 2; nn++){
      f32x4 s0 = nn ? s10 : s00;
      f32x4 s1 = nn ? s11 : s01;
      float tmax = fmaxf(fmaxf(fmaxf(s0[0],s0[1]), fmaxf(s0[2],s0[3])),
                         fmaxf(fmaxf(s1[0],s1[1]), fmaxf(s1[2],s1[3])));
      tmax = fmaxf(tmax, __shfl_xor(tmax, 16));
      tmax = fmaxf(tmax, __shfl_xor(tmax, 32));

      if (__any(tmax > mst[nn])){
        float mn = fmaxf(mst[nn], tmax);
        float sc = exp2_fast((mst[nn] - mn) * LOG2E);
        lst[nn] *= sc;
        #pragma unroll
        for (int i = 0; i < 16; i++){
          o_acc[nn][i][0]*=sc; o_acc[nn][i][1]*=sc;
          o_acc[nn][i][2]*=sc; o_acc[nn][i][3]*=sc;
        }
        mst[nn] = mn;
      }
      const float mb = mst[nn] * LOG2E;
      float p0 = exp2_fast(s0[0]*LOG2E - mb);
      float p1 = exp2_fast(s0[1]*LOG2E - mb);
      float p2 = exp2_fast(s0[2]*LOG2E - mb);
      float p3 = exp2_fast(s0[3]*LOG2E - mb);
      float p4 = exp2_fast(s1[0]*LOG2E - mb);
      float p5 = exp2_fast(s1[1]*LOG2E - mb);
      float p6 = exp2_fast(s1[2]*LOG2E - mb);
      float p7 = exp2_fast(s1[3]*LOG2E - mb);

      float psum = ((p0+p1)+(p2+p3)) + ((p4+p5)+(p6+p7));
      psum += __shfl_xor(psum, 16);
      psum += __shfl_xor(psum, 32);
      lst[nn] += psum;

      int W0 = pk_f16(p0, p1);
      int W1 = pk_f16(p2, p3);
      int W2 = pk_f16(p4, p5);
      int W3 = pk_f16(p6, p7);

      int a0 = __shfl(W0, laneA), a1 = __shfl(W1, laneA);
      int a2 = __shfl(W2, laneA), a3 = __shfl(W3, laneA);
      int b0 = __shfl(W0, laneB), b1 = __shfl(W1, laneB);
      int b2 = __shfl(W2, laneB), b3 = __shfl(W3, laneB);
      int4v ti;
      ti[0] = selLow ? a0 : a2;
      ti[1] = selLow ? a1 : a3;
      ti[2] = selLow ? b0 : b2;
      ti[3] = selLow ? b1 : b3;
      pf[nn] = __builtin_bit_cast(short8, ti);   // P[n][m = g*8 + j]
    }

    // ---- PV: V read shared by both nn
    __builtin_amdgcn_s_setprio(1);
    #pragma unroll
    for (int ct = 0; ct < 16; ct++){
      short8 vf = *(const short8*)(vbuf + ct*1024 + vb);
      o_acc[0][ct] = MFMAF16(vf, pf[0], o_acc[0][ct]);
      o_acc[1][ct] = MFMAF16(vf, pf[1], o_acc[1][ct]);
    }
    __builtin_amdgcn_s_setprio(0);

    cur = nxt;
    nxt = (nxt + 1 == 3) ? 0 : nxt + 1;
  }

  // ---- epilogue: partials in output layout ([.][c][n], coalesced along n)
  #pragma unroll
  for (int nn = 0; nn < 2; nn++){
    const int n = qbase + w*32 + nn*16 + col;
    if (kvq == 0){
      #pragma unroll
      for (int ct = 0; ct < 16; ct++)
        #pragma unroll
        for (int r = 0; r < 4; r++){
          int c = ct*16 + g*4 + r;
          outp[((size_t)(b*256 + c))*4096 + n] = o_acc[nn][ct][r];
        }
    } else {
      const size_t pbase = ((size_t)((kvq-1)*1024 + b*256))*4096;
      #pragma unroll
      for (int ct = 0; ct < 16; ct++)
        #pragma unroll
        for (int r = 0; r < 4; r++){
          int c = ct*16 + g*4 + r;
          part[pbase + (size_t)c*4096 + n] = f2h(o_acc[nn][ct][r]);
        }
    }
    if (g == 0){
      const size_t mb2 = ((size_t)(kvq*4 + b)*4096 + n)*2;
      mlbuf[mb2]     = mst[nn];
      mlbuf[mb2 + 1] = lst[nn];
    }
  }
}

// ---------------------------------------------------------------- merge splits
// Thread owns (row = b*256+c, 8 consecutive n): all reads/writes coalesced.
__global__ __launch_bounds__(256) void merge_kernel(
    const unsigned short* __restrict__ part, const float* __restrict__ mlbuf,
    float* __restrict__ out, int nsplit)
{
  const int T    = blockIdx.x*256 + threadIdx.x;   // 524288
  const int rowc = T >> 9;            // b*256 + c
  const int n8   = (T & 511) * 8;
  const int b    = rowc >> 8;

  float num[8], den[8], m[8];
  {
    f32x4 a0 = *(const f32x4*)&out[(size_t)rowc*4096 + n8];
    f32x4 a1 = *(const f32x4*)&out[(size_t)rowc*4096 + n8 + 4];
    const float* mlp = &mlbuf[((size_t)b*4096 + n8)*2];
    #pragma unroll
    for (int j = 0; j < 8; j++){
      m[j]   = mlp[j*2];
      den[j] = mlp[j*2 + 1];
      num[j] = (j < 4) ? a0[j] : a1[j-4];
    }
  }
  for (int s = 1; s < nsplit; s++){
    short8 pv = *(const short8*)&part[((size_t)((s-1)*1024 + rowc))*4096 + n8];
    const float* mlp = &mlbuf[((size_t)(s*4 + b)*4096 + n8)*2];
    #pragma unroll
    for (int j = 0; j < 8; j++){
      float ms = mlp[j*2], ls = mlp[j*2 + 1];
      unsigned short u = (unsigned short)pv[j];
      float ps = (float)*(const _Float16*)&u;
      float mn = fmaxf(m[j], ms);
      float sa = exp2_fast((m[j] - mn) * LOG2E);
      float sb = exp2_fast((ms   - mn) * LOG2E);
      num[j] = num[j]*sa + ps*sb;
      den[j] = den[j]*sa + ls*sb;
      m[j] = mn;
    }
  }
  f32x4 o0, o1;
  #pragma unroll
  for (int j = 0; j < 8; j++){
    float v = num[j] / den[j];
    if (j < 4) o0[j] = v; else o1[j-4] = v;
  }
  float* op = out + (size_t)rowc*4096 + n8;
  *(f32x4*)op       = o0;
  *(f32x4*)(op + 4) = o1;
}

// ---------------------------------------------------------------- launch
extern "C" void kernel_launch(void* const* d_in, const int* in_sizes, int n_in,
                              void* d_out, int out_size, void* d_ws, size_t ws_size,
                              hipStream_t stream)
{
  const float* x  = (const float*)d_in[0];
  const float* y  = (const float*)d_in[1];
  const float* Wq = (const float*)d_in[2];
  const float* bq = (const float*)d_in[3];
  const float* Wk = (const float*)d_in[4];
  const float* bk = (const float*)d_in[5];
  const float* Wv = (const float*)d_in[6];
  const float* bv = (const float*)d_in[7];
  float* out = (float*)d_out;

  char* ws = (char*)d_ws;
  const size_t MB = 1048576;
  unsigned short* qf   = (unsigned short*)(ws + 0*MB);
  unsigned short* kfp  = (unsigned short*)(ws + 8*MB);
  unsigned short* vtf  = (unsigned short*)(ws + 16*MB);
  unsigned short* wf   = (unsigned short*)(ws + 24*MB);
  unsigned short* part = (unsigned short*)(ws + 24*MB + 393216);

  // split 0 partials go to d_out; ws holds (nsplit-1) f16 planes + ml.
  const int nsplit = (ws_size >= 50*MB) ? 4 : 2;
  const int iters  = (4096 / nsplit) / 32;
  float* mlb = (float*)(ws + 24*MB + 393216 + (size_t)(nsplit-1)*8*MB);

  cvt_w<<<dim3(256,3), dim3(256), 0, stream>>>(Wq, Wk, Wv, wf);
  proj_kernel<<<dim3(64,4,3), dim3(256), 0, stream>>>(x, y, wf, bq, bk, bv,
                                                      qf, kfp, vtf);
  attn_kernel<<<dim3(64*nsplit), dim3(512), 0, stream>>>(qf, kfp, vtf, out, part,
                                                         mlb, nsplit, iters);
  merge_kernel<<<dim3(2048), dim3(256), 0, stream>>>(part, mlb, out, nsplit);
}